// Round 1
// baseline (576.069 us; speedup 1.0000x reference)
//
#include <hip/hip_runtime.h>
#include <stdint.h>

#define NB_    16384
#define SHIFT_ 18
#define CAP_   2048
#define KSEL   512
#define MAXDET 300
#define NTOT   87040
#define NIMG   16
#define SCORE_T 0.25f
#define NMS_T   0.45f

// level layout: offsets 0, 65536, 81920, 86016 ; W = 256,128,64,32 ; stride 8,16,32,64

__device__ __forceinline__ float sigmoidf_(float x) {
  return 1.0f / (1.0f + expf(-x));
}

__device__ __forceinline__ float load_cls_(const float* c0, const float* c1,
                                           const float* c2, const float* c3,
                                           int b, int n) {
  if (n < 65536) return c0[b * 65536 + n];
  if (n < 81920) return c1[b * 16384 + (n - 65536)];
  if (n < 86016) return c2[b * 4096  + (n - 81920)];
  return c3[b * 1024 + (n - 86016)];
}

// ---------------- pass 1: score histogram ----------------
__global__ void k_hist(const float* __restrict__ c0, const float* __restrict__ c1,
                       const float* __restrict__ c2, const float* __restrict__ c3,
                       uint32_t* __restrict__ hist) {
  int gid = blockIdx.x * blockDim.x + threadIdx.x;   // grid covers exactly NIMG*NTOT
  int b = gid / NTOT;
  int n = gid - b * NTOT;
  float s = sigmoidf_(load_cls_(c0, c1, c2, c3, b, n));
  if (s > SCORE_T) {
    uint32_t bits = __float_as_uint(s);
    atomicAdd(&hist[b * NB_ + (bits >> SHIFT_)], 1u);
  }
}

// ---------------- pass 2: per-image bit threshold ----------------
__global__ void k_thresh(const uint32_t* __restrict__ hist, uint32_t* __restrict__ thr) {
  const int b = blockIdx.x;
  const int t = threadIdx.x;            // 256 threads
  const int CH = NB_ / 256;             // 64 buckets per thread
  __shared__ uint32_t csum[256];
  __shared__ uint32_t suf[256];
  __shared__ int s_bucket;

  const uint32_t* h = hist + (size_t)b * NB_;
  uint32_t s = 0;
  for (int i = 0; i < CH; ++i) s += h[t * CH + i];
  csum[t] = s;
  if (t == 0) s_bucket = 0;
  __syncthreads();
  if (t == 0) {
    uint32_t a = 0;
    for (int i = 255; i >= 0; --i) { suf[i] = a; a += csum[i]; }
  }
  __syncthreads();
  // find largest bucket T with (count of bits in buckets >= T) >= KSEL
  uint32_t a = suf[t];
  if (a < KSEL) {
    for (int i = CH - 1; i >= 0; --i) {
      a += h[t * CH + i];
      if (a >= KSEL) { s_bucket = t * CH + i; break; }
    }
  }
  __syncthreads();
  if (t == 0) thr[b] = ((uint32_t)s_bucket) << SHIFT_;
}

// ---------------- pass 3: compact candidates ----------------
__global__ void k_compact(const float* __restrict__ c0, const float* __restrict__ c1,
                          const float* __restrict__ c2, const float* __restrict__ c3,
                          const uint32_t* __restrict__ thr,
                          uint32_t* __restrict__ cnt, uint64_t* __restrict__ keys) {
  int gid = blockIdx.x * blockDim.x + threadIdx.x;
  int b = gid / NTOT;
  int n = gid - b * NTOT;
  float s = sigmoidf_(load_cls_(c0, c1, c2, c3, b, n));
  if (s > SCORE_T) {
    uint32_t bits = __float_as_uint(s);
    if (bits >= thr[b]) {
      uint32_t pos = atomicAdd(&cnt[b], 1u);
      if (pos < CAP_) {
        keys[(size_t)b * CAP_ + pos] =
            ((uint64_t)bits << 32) | (uint32_t)(0xFFFFFFFFu - (uint32_t)n);
      }
    }
  }
}

// ---------------- pass 4: sort + decode + NMS + output ----------------
__global__ __launch_bounds__(1024)
void k_main(const float* __restrict__ r0, const float* __restrict__ r1,
            const float* __restrict__ r2, const float* __restrict__ r3,
            const float* __restrict__ p0, const float* __restrict__ p1,
            const float* __restrict__ p2, const float* __restrict__ p3,
            const uint64_t* __restrict__ keys, const uint32_t* __restrict__ cnt,
            float* __restrict__ out) {
  const int b = blockIdx.x;
  const int tid = threadIdx.x;

  __shared__ uint64_t sk[CAP_];          // 16 KB
  __shared__ float    bx[KSEL][4];       // 8 KB
  __shared__ float    barea[KSEL];       // 2 KB
  __shared__ uint64_t sup[KSEL][8];      // 32 KB
  __shared__ uint64_t keepW[8];
  __shared__ int      s_nkept;

  int c = (int)cnt[b];
  if (c > CAP_) c = CAP_;
  for (int i = tid; i < CAP_; i += 1024)
    sk[i] = (i < c) ? keys[(size_t)b * CAP_ + i] : 0ull;
  __syncthreads();

  // bitonic sort, descending
  for (int k = 2; k <= CAP_; k <<= 1) {
    for (int j = k >> 1; j > 0; j >>= 1) {
      for (int i = tid; i < CAP_; i += 1024) {
        int ixj = i ^ j;
        if (ixj > i) {
          uint64_t a = sk[i], d = sk[ixj];
          bool asc = (i & k) != 0;
          bool swap = asc ? (a > d) : (a < d);
          if (swap) { sk[i] = d; sk[ixj] = a; }
        }
      }
      __syncthreads();
    }
  }

  // decode top-512 boxes (reference float32 formulas)
  if (tid < KSEL) {
    uint64_t key = sk[tid];
    float sc = __uint_as_float((uint32_t)(key >> 32));
    float x1 = 0.f, y1 = 0.f, x2 = 0.f, y2 = 0.f;
    if (sc > SCORE_T) {
      int n = (int)(0xFFFFFFFFu - (uint32_t)key);
      const float* rp; int local, Nl, logW; float st;
      if (n < 65536)      { rp = r0 + (size_t)b * 4 * 65536; local = n;          Nl = 65536; logW = 8; st = 8.f;  }
      else if (n < 81920) { rp = r1 + (size_t)b * 4 * 16384; local = n - 65536;  Nl = 16384; logW = 7; st = 16.f; }
      else if (n < 86016) { rp = r2 + (size_t)b * 4 * 4096;  local = n - 81920;  Nl = 4096;  logW = 6; st = 32.f; }
      else                { rp = r3 + (size_t)b * 4 * 1024;  local = n - 86016;  Nl = 1024;  logW = 5; st = 64.f; }
      int y = local >> logW, x = local & ((1 << logW) - 1);
      float cx = ((float)x + 0.5f) * st;
      float cy = ((float)y + 0.5f) * st;
      float rv0 = rp[local];
      float rv1 = rp[Nl + local];
      float rv2 = rp[2 * Nl + local];
      float rv3 = rp[3 * Nl + local];
      float cxd = cx + rv0 * st;
      float cyd = cy + rv1 * st;
      float w = expf(rv2) * st;
      float h = expf(rv3) * st;
      x1 = cxd - w * 0.5f; y1 = cyd - h * 0.5f;
      x2 = cxd + w * 0.5f; y2 = cyd + h * 0.5f;
    }
    bx[tid][0] = x1; bx[tid][1] = y1; bx[tid][2] = x2; bx[tid][3] = y2;
    barea[tid] = (x2 - x1) * (y2 - y1);
  }
  __syncthreads();

  // valid mask via wave ballot (waves 0..7, word = wave)
  {
    int wave = tid >> 6, lane = tid & 63;
    if (wave < 8) {
      int i = (wave << 6) | lane;
      float sc = __uint_as_float((uint32_t)(sk[i] >> 32));
      unsigned long long v = __ballot(sc > SCORE_T);
      if (lane == 0) keepW[wave] = v;
    }
  }
  __syncthreads();

  // suppression matrix: sup[i][w] bit j-w*64 set iff (j>i) && IoU(i,j) > NMS_T
  {
    int wave = tid >> 6, lane = tid & 63;   // 16 waves
    for (int task = wave; task < KSEL * 8; task += 16) {
      int i = task >> 3, w = task & 7;
      int j = (w << 6) | lane;
      float xi1 = bx[i][0], yi1 = bx[i][1], xi2 = bx[i][2], yi2 = bx[i][3];
      float ai = barea[i];
      float xx1 = fmaxf(xi1, bx[j][0]);
      float yy1 = fmaxf(yi1, bx[j][1]);
      float xx2 = fminf(xi2, bx[j][2]);
      float yy2 = fminf(yi2, bx[j][3]);
      float inter = fmaxf(xx2 - xx1, 0.f) * fmaxf(yy2 - yy1, 0.f);
      float uni = ai + barea[j] - inter;
      float iou = inter / fmaxf(uni, 1e-9f);
      bool pred = (j > i) && (iou > NMS_T);
      unsigned long long word = __ballot(pred);
      if (lane == 0) sup[i][w] = word;
    }
  }
  __syncthreads();

  // sequential greedy sweep (thread 0), keep mask in statically-indexed regs
  if (tid == 0) {
    uint64_t kw[8];
#pragma unroll
    for (int w = 0; w < 8; ++w) kw[w] = keepW[w];
#pragma unroll
    for (int w = 0; w < 8; ++w) {
      for (int bit = 0; bit < 64; ++bit) {
        if ((kw[w] >> bit) & 1ull) {
          int i = (w << 6) | bit;
#pragma unroll
          for (int u = 0; u < 8; ++u) kw[u] &= ~sup[i][u];
        }
      }
    }
    int nk = 0;
#pragma unroll
    for (int w = 0; w < 8; ++w) { keepW[w] = kw[w]; nk += __popcll(kw[w]); }
    s_nkept = nk;
  }
  __syncthreads();

  int nwrite = s_nkept; if (nwrite > MAXDET) nwrite = MAXDET;

  // write kept rows
  if (tid < KSEL) {
    int w = tid >> 6, bit = tid & 63;
    bool kept = (keepW[w] >> bit) & 1ull;
    if (kept) {
      int r = 0;
#pragma unroll
      for (int u = 0; u < 8; ++u) {
        uint64_t m = keepW[u];
        if (u < w) r += __popcll(m);
        else if (u == w) r += __popcll(m & ((bit == 0) ? 0ull : ((1ull << bit) - 1ull)));
      }
      if (r < MAXDET) {
        uint64_t key = sk[tid];
        float sc = __uint_as_float((uint32_t)(key >> 32));
        int n = (int)(0xFFFFFFFFu - (uint32_t)key);
        const float* kp; int local, Nl, logW; float st;
        if (n < 65536)      { kp = p0 + (size_t)b * 10 * 65536; local = n;          Nl = 65536; logW = 8; st = 8.f;  }
        else if (n < 81920) { kp = p1 + (size_t)b * 10 * 16384; local = n - 65536;  Nl = 16384; logW = 7; st = 16.f; }
        else if (n < 86016) { kp = p2 + (size_t)b * 10 * 4096;  local = n - 81920;  Nl = 4096;  logW = 6; st = 32.f; }
        else                { kp = p3 + (size_t)b * 10 * 1024;  local = n - 86016;  Nl = 1024;  logW = 5; st = 64.f; }
        int y = local >> logW, x = local & ((1 << logW) - 1);
        float cx = ((float)x + 0.5f) * st;
        float cy = ((float)y + 0.5f) * st;
        float* o = out + ((size_t)b * MAXDET + r) * 15;
        o[0] = bx[tid][0]; o[1] = bx[tid][1]; o[2] = bx[tid][2]; o[3] = bx[tid][3];
        o[4] = sc;
#pragma unroll
        for (int q = 0; q < 5; ++q) {
          float kx = cx + kp[(2 * q) * Nl + local] * st;
          float ky = cy + kp[(2 * q + 1) * Nl + local] * st;
          o[5 + 2 * q] = kx;
          o[6 + 2 * q] = ky;
        }
      }
    }
  }

  // zero-fill remaining rows
  if (tid < MAXDET && tid >= nwrite) {
    float* o = out + ((size_t)b * MAXDET + tid) * 15;
#pragma unroll
    for (int e = 0; e < 15; ++e) o[e] = 0.f;
  }
}

extern "C" void kernel_launch(void* const* d_in, const int* in_sizes, int n_in,
                              void* d_out, int out_size, void* d_ws, size_t ws_size,
                              hipStream_t stream) {
  // dict order: cls0,reg0,kpt0, cls1,reg1,kpt1, cls2,reg2,kpt2, cls3,reg3,kpt3
  const float* cls0 = (const float*)d_in[0];
  const float* reg0 = (const float*)d_in[1];
  const float* kpt0 = (const float*)d_in[2];
  const float* cls1 = (const float*)d_in[3];
  const float* reg1 = (const float*)d_in[4];
  const float* kpt1 = (const float*)d_in[5];
  const float* cls2 = (const float*)d_in[6];
  const float* reg2 = (const float*)d_in[7];
  const float* kpt2 = (const float*)d_in[8];
  const float* cls3 = (const float*)d_in[9];
  const float* reg3 = (const float*)d_in[10];
  const float* kpt3 = (const float*)d_in[11];
  float* out = (float*)d_out;

  uint8_t* ws = (uint8_t*)d_ws;
  const size_t histB = (size_t)NIMG * NB_ * sizeof(uint32_t);   // 1 MiB
  uint32_t* hist = (uint32_t*)ws;
  uint32_t* cnt  = (uint32_t*)(ws + histB);
  uint32_t* thr  = (uint32_t*)(ws + histB + 64);
  uint64_t* keys = (uint64_t*)(ws + histB + 128);               // 8-aligned

  hipMemsetAsync(ws, 0, histB + 128, stream);

  const int total = NIMG * NTOT;                                 // 1,392,640 = 5440*256
  k_hist<<<total / 256, 256, 0, stream>>>(cls0, cls1, cls2, cls3, hist);
  k_thresh<<<NIMG, 256, 0, stream>>>(hist, thr);
  k_compact<<<total / 256, 256, 0, stream>>>(cls0, cls1, cls2, cls3, thr, cnt, keys);
  k_main<<<NIMG, 1024, 0, stream>>>(reg0, reg1, reg2, reg3,
                                    kpt0, kpt1, kpt2, kpt3,
                                    keys, cnt, out);
}

// Round 2
// 183.766 us; speedup vs baseline: 3.1348x; 3.1348x over previous
//
#include <hip/hip_runtime.h>
#include <stdint.h>

#define CAP_   2048
#define KSEL   512
#define MAXDET 300
#define NIMG   16
#define SCORE_T 0.25f
#define NMS_T   0.45f
#define HBINS  72          // 65 used (buckets 4000..4064 of bits>>18)
#define NGRP   21760       // 87040 anchors / 4 per float4 group
#define SLICES 8
#define PERSLICE 2720      // NGRP / SLICES

// group-level boundaries (float4 groups): 16384, 20480, 21504, 21760
// anchor-level boundaries: 65536, 81920, 86016, 87040 ; strides 8,16,32,64

__device__ __forceinline__ float sigmoidf_(float x) {
  return 1.0f / (1.0f + expf(-x));
}

__device__ __forceinline__ float4 load_cls4_(const float* c0, const float* c1,
                                             const float* c2, const float* c3,
                                             int b, int g) {
  if (g < 16384) return ((const float4*)(c0 + (size_t)b * 65536))[g];
  if (g < 20480) return ((const float4*)(c1 + (size_t)b * 16384))[g - 16384];
  if (g < 21504) return ((const float4*)(c2 + (size_t)b * 4096))[g - 20480];
  return ((const float4*)(c3 + (size_t)b * 1024))[g - 21504];
}

// ---------------- pass 1: 65-bin score histogram, LDS-privatized ----------------
__global__ __launch_bounds__(1024)
void k_scan(const float* __restrict__ c0, const float* __restrict__ c1,
            const float* __restrict__ c2, const float* __restrict__ c3,
            uint32_t* __restrict__ hist) {
  const int b = blockIdx.x >> 3;          // 8 slices per image
  const int slice = blockIdx.x & 7;
  const int tid = threadIdx.x;
  const int wave = tid >> 6;

  __shared__ uint32_t lh[16][HBINS];
  for (int i = tid; i < 16 * HBINS; i += 1024) ((uint32_t*)lh)[i] = 0;
  __syncthreads();

  for (int it = 0; it < 3; ++it) {
    int lg = it * 1024 + tid;
    if (lg < PERSLICE) {
      int g = slice * PERSLICE + lg;
      float4 v = load_cls4_(c0, c1, c2, c3, b, g);
      float sv[4] = {v.x, v.y, v.z, v.w};
#pragma unroll
      for (int e = 0; e < 4; ++e) {
        float s = sigmoidf_(sv[e]);
        if (s > SCORE_T) {
          uint32_t bin = (__float_as_uint(s) >> 18) - 4000u;
          if (bin > 64u) bin = 64u;
          atomicAdd(&lh[wave][bin], 1u);
        }
      }
    }
  }
  __syncthreads();

  if (tid < HBINS) {
    uint32_t s = 0;
#pragma unroll
    for (int w = 0; w < 16; ++w) s += lh[w][tid];
    if (s) atomicAdd(&hist[b * HBINS + tid], s);
  }
}

// ---------------- pass 2: per-image bit threshold (1 wave per image) ----------------
__global__ void k_thresh(const uint32_t* __restrict__ hist, uint32_t* __restrict__ thr) {
  const int b = blockIdx.x;
  const int lane = threadIdx.x;           // 64 threads
  uint32_t x = hist[b * HBINS + lane];
  if (lane == 63) x += hist[b * HBINS + 64];   // fold bin 64 into 63

  // inclusive suffix scan: x[t] = sum_{t'=t..63} cnt[t']
  for (int off = 1; off < 64; off <<= 1) {
    uint32_t v = __shfl_down(x, off);
    if (lane + off < 64) x += v;
  }
  uint32_t nxt = __shfl_down(x, 1);
  if (lane == 63) nxt = 0;
  bool cross = (x >= KSEL) && (nxt < KSEL);   // unique lane (x non-increasing)
  unsigned long long m = __ballot(cross);
  if (lane == 0) {
    int bucket = m ? (__ffsll(m) - 1) : 0;
    thr[b] = ((uint32_t)(4000 + bucket)) << 18;
  }
}

// ---------------- pass 3: compact candidates via LDS list ----------------
__global__ __launch_bounds__(1024)
void k_compact(const float* __restrict__ c0, const float* __restrict__ c1,
               const float* __restrict__ c2, const float* __restrict__ c3,
               const uint32_t* __restrict__ thr,
               uint32_t* __restrict__ cnt, uint64_t* __restrict__ keys) {
  const int b = blockIdx.x >> 3;
  const int slice = blockIdx.x & 7;
  const int tid = threadIdx.x;

  __shared__ uint64_t lk[CAP_];
  __shared__ uint32_t lcnt;
  __shared__ uint32_t gbase;
  if (tid == 0) lcnt = 0;
  __syncthreads();

  const uint32_t tb = thr[b];             // block-uniform

  for (int it = 0; it < 3; ++it) {
    int lg = it * 1024 + tid;
    if (lg < PERSLICE) {
      int g = slice * PERSLICE + lg;
      float4 v = load_cls4_(c0, c1, c2, c3, b, g);
      float sv[4] = {v.x, v.y, v.z, v.w};
#pragma unroll
      for (int e = 0; e < 4; ++e) {
        float s = sigmoidf_(sv[e]);
        if (s > SCORE_T) {
          uint32_t bits = __float_as_uint(s);
          if (bits >= tb) {
            uint32_t n = (uint32_t)(4 * g + e);
            uint32_t p = atomicAdd(&lcnt, 1u);
            if (p < CAP_)
              lk[p] = ((uint64_t)bits << 32) | (0xFFFFFFFFu - n);
          }
        }
      }
    }
  }
  __syncthreads();

  if (tid == 0) {
    uint32_t c = lcnt > CAP_ ? CAP_ : lcnt;
    gbase = atomicAdd(&cnt[b], c);
  }
  __syncthreads();

  uint32_t c = lcnt > CAP_ ? CAP_ : lcnt;
  for (uint32_t i = tid; i < c; i += 1024) {
    uint32_t pos = gbase + i;
    if (pos < CAP_) keys[(size_t)b * CAP_ + pos] = lk[i];
  }
}

// ---------------- pass 4: sort + decode + NMS + output ----------------
__global__ __launch_bounds__(1024)
void k_main(const float* __restrict__ r0, const float* __restrict__ r1,
            const float* __restrict__ r2, const float* __restrict__ r3,
            const float* __restrict__ p0, const float* __restrict__ p1,
            const float* __restrict__ p2, const float* __restrict__ p3,
            const uint64_t* __restrict__ keys, const uint32_t* __restrict__ cnt,
            float* __restrict__ out) {
  const int b = blockIdx.x;
  const int tid = threadIdx.x;

  __shared__ uint64_t sk[CAP_];          // 16 KB
  __shared__ float    bx[KSEL][4];       // 8 KB
  __shared__ float    barea[KSEL];       // 2 KB
  __shared__ uint64_t sup[KSEL][8];      // 32 KB
  __shared__ uint64_t keepW[8];
  __shared__ int      s_nkept;

  int c = (int)cnt[b];
  if (c > CAP_) c = CAP_;
  for (int i = tid; i < CAP_; i += 1024)
    sk[i] = (i < c) ? keys[(size_t)b * CAP_ + i] : 0ull;
  __syncthreads();

  // bitonic sort, descending
  for (int k = 2; k <= CAP_; k <<= 1) {
    for (int j = k >> 1; j > 0; j >>= 1) {
      for (int i = tid; i < CAP_; i += 1024) {
        int ixj = i ^ j;
        if (ixj > i) {
          uint64_t a = sk[i], d = sk[ixj];
          bool asc = (i & k) != 0;
          bool swap = asc ? (a > d) : (a < d);
          if (swap) { sk[i] = d; sk[ixj] = a; }
        }
      }
      __syncthreads();
    }
  }

  // decode top-512 boxes (reference float32 formulas)
  if (tid < KSEL) {
    uint64_t key = sk[tid];
    float sc = __uint_as_float((uint32_t)(key >> 32));
    float x1 = 0.f, y1 = 0.f, x2 = 0.f, y2 = 0.f;
    if (sc > SCORE_T) {
      int n = (int)(0xFFFFFFFFu - (uint32_t)key);
      const float* rp; int local, Nl, logW; float st;
      if (n < 65536)      { rp = r0 + (size_t)b * 4 * 65536; local = n;          Nl = 65536; logW = 8; st = 8.f;  }
      else if (n < 81920) { rp = r1 + (size_t)b * 4 * 16384; local = n - 65536;  Nl = 16384; logW = 7; st = 16.f; }
      else if (n < 86016) { rp = r2 + (size_t)b * 4 * 4096;  local = n - 81920;  Nl = 4096;  logW = 6; st = 32.f; }
      else                { rp = r3 + (size_t)b * 4 * 1024;  local = n - 86016;  Nl = 1024;  logW = 5; st = 64.f; }
      int y = local >> logW, x = local & ((1 << logW) - 1);
      float cx = ((float)x + 0.5f) * st;
      float cy = ((float)y + 0.5f) * st;
      float rv0 = rp[local];
      float rv1 = rp[Nl + local];
      float rv2 = rp[2 * Nl + local];
      float rv3 = rp[3 * Nl + local];
      float cxd = cx + rv0 * st;
      float cyd = cy + rv1 * st;
      float w = expf(rv2) * st;
      float h = expf(rv3) * st;
      x1 = cxd - w * 0.5f; y1 = cyd - h * 0.5f;
      x2 = cxd + w * 0.5f; y2 = cyd + h * 0.5f;
    }
    bx[tid][0] = x1; bx[tid][1] = y1; bx[tid][2] = x2; bx[tid][3] = y2;
    barea[tid] = (x2 - x1) * (y2 - y1);
  }
  __syncthreads();

  // valid mask via wave ballot (waves 0..7, word = wave)
  {
    int wave = tid >> 6, lane = tid & 63;
    if (wave < 8) {
      int i = (wave << 6) | lane;
      float sc = __uint_as_float((uint32_t)(sk[i] >> 32));
      unsigned long long v = __ballot(sc > SCORE_T);
      if (lane == 0) keepW[wave] = v;
    }
  }
  __syncthreads();

  // suppression matrix: sup[i][w] bit (j - w*64) set iff (j>i) && IoU(i,j) > NMS_T
  {
    int wave = tid >> 6, lane = tid & 63;   // 16 waves
    for (int task = wave; task < KSEL * 8; task += 16) {
      int i = task >> 3, w = task & 7;
      int j = (w << 6) | lane;
      float xi1 = bx[i][0], yi1 = bx[i][1], xi2 = bx[i][2], yi2 = bx[i][3];
      float ai = barea[i];
      float xx1 = fmaxf(xi1, bx[j][0]);
      float yy1 = fmaxf(yi1, bx[j][1]);
      float xx2 = fminf(xi2, bx[j][2]);
      float yy2 = fminf(yi2, bx[j][3]);
      float inter = fmaxf(xx2 - xx1, 0.f) * fmaxf(yy2 - yy1, 0.f);
      float uni = ai + barea[j] - inter;
      float iou = inter / fmaxf(uni, 1e-9f);
      bool pred = (j > i) && (iou > NMS_T);
      unsigned long long word = __ballot(pred);
      if (lane == 0) sup[i][w] = word;
    }
  }
  __syncthreads();

  // sequential greedy sweep (thread 0), keep mask in statically-indexed regs
  if (tid == 0) {
    uint64_t kw[8];
#pragma unroll
    for (int w = 0; w < 8; ++w) kw[w] = keepW[w];
#pragma unroll
    for (int w = 0; w < 8; ++w) {
      for (int bit = 0; bit < 64; ++bit) {
        if ((kw[w] >> bit) & 1ull) {
          int i = (w << 6) | bit;
#pragma unroll
          for (int u = 0; u < 8; ++u) kw[u] &= ~sup[i][u];
        }
      }
    }
    int nk = 0;
#pragma unroll
    for (int w = 0; w < 8; ++w) { keepW[w] = kw[w]; nk += __popcll(kw[w]); }
    s_nkept = nk;
  }
  __syncthreads();

  int nwrite = s_nkept; if (nwrite > MAXDET) nwrite = MAXDET;

  // write kept rows
  if (tid < KSEL) {
    int w = tid >> 6, bit = tid & 63;
    bool kept = (keepW[w] >> bit) & 1ull;
    if (kept) {
      int r = 0;
#pragma unroll
      for (int u = 0; u < 8; ++u) {
        uint64_t m = keepW[u];
        if (u < w) r += __popcll(m);
        else if (u == w) r += __popcll(m & ((bit == 0) ? 0ull : ((1ull << bit) - 1ull)));
      }
      if (r < MAXDET) {
        uint64_t key = sk[tid];
        float sc = __uint_as_float((uint32_t)(key >> 32));
        int n = (int)(0xFFFFFFFFu - (uint32_t)key);
        const float* kp; int local, Nl, logW; float st;
        if (n < 65536)      { kp = p0 + (size_t)b * 10 * 65536; local = n;          Nl = 65536; logW = 8; st = 8.f;  }
        else if (n < 81920) { kp = p1 + (size_t)b * 10 * 16384; local = n - 65536;  Nl = 16384; logW = 7; st = 16.f; }
        else if (n < 86016) { kp = p2 + (size_t)b * 10 * 4096;  local = n - 81920;  Nl = 4096;  logW = 6; st = 32.f; }
        else                { kp = p3 + (size_t)b * 10 * 1024;  local = n - 86016;  Nl = 1024;  logW = 5; st = 64.f; }
        int y = local >> logW, x = local & ((1 << logW) - 1);
        float cx = ((float)x + 0.5f) * st;
        float cy = ((float)y + 0.5f) * st;
        float* o = out + ((size_t)b * MAXDET + r) * 15;
        o[0] = bx[tid][0]; o[1] = bx[tid][1]; o[2] = bx[tid][2]; o[3] = bx[tid][3];
        o[4] = sc;
#pragma unroll
        for (int q = 0; q < 5; ++q) {
          float kx = cx + kp[(2 * q) * Nl + local] * st;
          float ky = cy + kp[(2 * q + 1) * Nl + local] * st;
          o[5 + 2 * q] = kx;
          o[6 + 2 * q] = ky;
        }
      }
    }
  }

  // zero-fill remaining rows
  if (tid < MAXDET && tid >= nwrite) {
    float* o = out + ((size_t)b * MAXDET + tid) * 15;
#pragma unroll
    for (int e = 0; e < 15; ++e) o[e] = 0.f;
  }
}

extern "C" void kernel_launch(void* const* d_in, const int* in_sizes, int n_in,
                              void* d_out, int out_size, void* d_ws, size_t ws_size,
                              hipStream_t stream) {
  // dict order: cls0,reg0,kpt0, cls1,reg1,kpt1, cls2,reg2,kpt2, cls3,reg3,kpt3
  const float* cls0 = (const float*)d_in[0];
  const float* reg0 = (const float*)d_in[1];
  const float* kpt0 = (const float*)d_in[2];
  const float* cls1 = (const float*)d_in[3];
  const float* reg1 = (const float*)d_in[4];
  const float* kpt1 = (const float*)d_in[5];
  const float* cls2 = (const float*)d_in[6];
  const float* reg2 = (const float*)d_in[7];
  const float* kpt2 = (const float*)d_in[8];
  const float* cls3 = (const float*)d_in[9];
  const float* reg3 = (const float*)d_in[10];
  const float* kpt3 = (const float*)d_in[11];
  float* out = (float*)d_out;

  uint8_t* ws = (uint8_t*)d_ws;
  // layout: hist 16*72*4 = 4608 B | cnt 64 B | thr 64 B | pad -> keys @ 8192
  uint32_t* hist = (uint32_t*)ws;
  uint32_t* cnt  = (uint32_t*)(ws + 4608);
  uint32_t* thr  = (uint32_t*)(ws + 4672);
  uint64_t* keys = (uint64_t*)(ws + 8192);   // 16*2048*8 = 256 KiB

  hipMemsetAsync(ws, 0, 8192, stream);

  k_scan<<<NIMG * SLICES, 1024, 0, stream>>>(cls0, cls1, cls2, cls3, hist);
  k_thresh<<<NIMG, 64, 0, stream>>>(hist, thr);
  k_compact<<<NIMG * SLICES, 1024, 0, stream>>>(cls0, cls1, cls2, cls3, thr, cnt, keys);
  k_main<<<NIMG, 1024, 0, stream>>>(reg0, reg1, reg2, reg3,
                                    kpt0, kpt1, kpt2, kpt3,
                                    keys, cnt, out);
}

// Round 4
// 111.538 us; speedup vs baseline: 5.1648x; 1.6476x over previous
//
#include <hip/hip_runtime.h>
#include <stdint.h>

#define CAP_   2048
#define KSEL   512
#define MAXDET 300
#define NIMG   16
#define SCORE_T 0.25f
#define NMS_T   0.45f
#define HBINS  72          // 65 used (buckets 4000..4064 of bits>>18)
#define SLICES 8
#define PERSLICE 2720      // (87040/4) / 8

// anchor-level boundaries: 65536, 81920, 86016, 87040 ; strides 8,16,32,64
// float4-group boundaries: 16384, 20480, 21504, 21760

__device__ __forceinline__ float sigmoidf_(float x) {
  return 1.0f / (1.0f + expf(-x));
}

__device__ __forceinline__ float4 load_cls4_(const float* c0, const float* c1,
                                             const float* c2, const float* c3,
                                             int b, int g) {
  if (g < 16384) return ((const float4*)(c0 + (size_t)b * 65536))[g];
  if (g < 20480) return ((const float4*)(c1 + (size_t)b * 16384))[g - 16384];
  if (g < 21504) return ((const float4*)(c2 + (size_t)b * 4096))[g - 20480];
  return ((const float4*)(c3 + (size_t)b * 1024))[g - 21504];
}

// ---------------- pass 1: 65-bin score histogram, LDS-privatized ----------------
__global__ __launch_bounds__(1024)
void k_scan(const float* __restrict__ c0, const float* __restrict__ c1,
            const float* __restrict__ c2, const float* __restrict__ c3,
            uint32_t* __restrict__ hist) {
  const int b = blockIdx.x >> 3;
  const int slice = blockIdx.x & 7;
  const int tid = threadIdx.x;
  const int wave = tid >> 6;

  __shared__ uint32_t lh[16][HBINS];
  for (int i = tid; i < 16 * HBINS; i += 1024) ((uint32_t*)lh)[i] = 0;
  __syncthreads();

  for (int it = 0; it < 3; ++it) {
    int lg = it * 1024 + tid;
    if (lg < PERSLICE) {
      int g = slice * PERSLICE + lg;
      float4 v = load_cls4_(c0, c1, c2, c3, b, g);
      float sv[4] = {v.x, v.y, v.z, v.w};
#pragma unroll
      for (int e = 0; e < 4; ++e) {
        float s = sigmoidf_(sv[e]);
        if (s > SCORE_T) {
          uint32_t bin = (__float_as_uint(s) >> 18) - 4000u;
          if (bin > 64u) bin = 64u;
          atomicAdd(&lh[wave][bin], 1u);
        }
      }
    }
  }
  __syncthreads();

  if (tid < HBINS) {
    uint32_t s = 0;
#pragma unroll
    for (int w = 0; w < 16; ++w) s += lh[w][tid];
    if (s) atomicAdd(&hist[b * HBINS + tid], s);
  }
}

// ---------------- pass 2: per-image bit threshold (1 wave per image) ----------------
__global__ void k_thresh(const uint32_t* __restrict__ hist, uint32_t* __restrict__ thr) {
  const int b = blockIdx.x;
  const int lane = threadIdx.x;           // 64 threads
  uint32_t x = hist[b * HBINS + lane];
  if (lane == 63) x += hist[b * HBINS + 64];

  for (int off = 1; off < 64; off <<= 1) {
    uint32_t v = __shfl_down(x, off);
    if (lane + off < 64) x += v;
  }
  uint32_t nxt = __shfl_down(x, 1);
  if (lane == 63) nxt = 0;
  bool cross = (x >= KSEL) && (nxt < KSEL);
  unsigned long long m = __ballot(cross);
  if (lane == 0) {
    int bucket = m ? (__ffsll(m) - 1) : 0;
    thr[b] = ((uint32_t)(4000 + bucket)) << 18;
  }
}

// ---------------- pass 3: compact candidates via LDS list ----------------
__global__ __launch_bounds__(1024)
void k_compact(const float* __restrict__ c0, const float* __restrict__ c1,
               const float* __restrict__ c2, const float* __restrict__ c3,
               const uint32_t* __restrict__ thr,
               uint32_t* __restrict__ cnt, uint64_t* __restrict__ keys) {
  const int b = blockIdx.x >> 3;
  const int slice = blockIdx.x & 7;
  const int tid = threadIdx.x;

  __shared__ uint64_t lk[CAP_];
  __shared__ uint32_t lcnt;
  __shared__ uint32_t gbase;
  if (tid == 0) lcnt = 0;
  __syncthreads();

  const uint32_t tb = thr[b];

  for (int it = 0; it < 3; ++it) {
    int lg = it * 1024 + tid;
    if (lg < PERSLICE) {
      int g = slice * PERSLICE + lg;
      float4 v = load_cls4_(c0, c1, c2, c3, b, g);
      float sv[4] = {v.x, v.y, v.z, v.w};
#pragma unroll
      for (int e = 0; e < 4; ++e) {
        float s = sigmoidf_(sv[e]);
        if (s > SCORE_T) {
          uint32_t bits = __float_as_uint(s);
          if (bits >= tb) {
            uint32_t n = (uint32_t)(4 * g + e);
            uint32_t p = atomicAdd(&lcnt, 1u);
            if (p < CAP_)
              lk[p] = ((uint64_t)bits << 32) | (0xFFFFFFFFu - n);
          }
        }
      }
    }
  }
  __syncthreads();

  if (tid == 0) {
    uint32_t c = lcnt > CAP_ ? CAP_ : lcnt;
    gbase = atomicAdd(&cnt[b], c);
  }
  __syncthreads();

  uint32_t c = lcnt > CAP_ ? CAP_ : lcnt;
  for (uint32_t i = tid; i < c; i += 1024) {
    uint32_t pos = gbase + i;
    if (pos < CAP_) keys[(size_t)b * CAP_ + pos] = lk[i];
  }
}

// ---------------- pass 4: hybrid register/LDS bitonic sort + decode ----------------
__device__ __forceinline__ uint64_t cmpex_(uint64_t a, uint64_t b, bool takemax) {
  bool agtb = a > b;
  return (takemax == agtb) ? a : b;
}

__global__ __launch_bounds__(1024)
void k_sort(const uint64_t* __restrict__ keys, const uint32_t* __restrict__ cnt,
            const float* __restrict__ r0p, const float* __restrict__ r1p,
            const float* __restrict__ r2p, const float* __restrict__ r3p,
            uint64_t* __restrict__ skeys, float* __restrict__ bxs) {
  const int b = blockIdx.x;
  const int t = threadIdx.x;

  __shared__ uint64_t sk[CAP_];          // 16 KB

  int c = (int)cnt[b];
  if (c > CAP_) c = CAP_;
  uint64_t r0 = (t < c)        ? keys[(size_t)b * CAP_ + t]        : 0ull;
  uint64_t r1 = (t + 1024 < c) ? keys[(size_t)b * CAP_ + t + 1024] : 0ull;

  // element i0 = t held in r0, element i1 = t+1024 held in r1; descending sort
  for (int k = 2; k <= CAP_; k <<= 1) {
    bool asc0 = (t & k) != 0;
    bool asc1 = ((t + 1024) & k) != 0;
    int j = k >> 1;
    if (j == 1024) {            // k==2048: partner is own other register; both desc
      if (r0 < r1) { uint64_t tmp = r0; r0 = r1; r1 = tmp; }
      j = 512;
    }
    for (; j >= 64; j >>= 1) {  // cross-wave rounds via LDS
      sk[t] = r0; sk[t + 1024] = r1;
      __syncthreads();
      uint64_t u0 = sk[t ^ j];
      uint64_t u1 = sk[(t ^ j) + 1024];
      __syncthreads();
      bool lo = (t & j) == 0;
      r0 = cmpex_(r0, u0, asc0 ? !lo : lo);
      r1 = cmpex_(r1, u1, asc1 ? !lo : lo);
    }
    for (; j >= 1; j >>= 1) {   // intra-wave rounds via shuffle
      uint64_t u0 = __shfl_xor((unsigned long long)r0, j);
      uint64_t u1 = __shfl_xor((unsigned long long)r1, j);
      bool lo = (t & j) == 0;
      r0 = cmpex_(r0, u0, asc0 ? !lo : lo);
      r1 = cmpex_(r1, u1, asc1 ? !lo : lo);
    }
  }
  sk[t] = r0; sk[t + 1024] = r1;
  __syncthreads();

  // decode top-512 boxes, store keys + SoA boxes/areas to workspace
  if (t < KSEL) {
    uint64_t key = sk[t];
    float sc = __uint_as_float((uint32_t)(key >> 32));
    float x1 = 0.f, y1 = 0.f, x2 = 0.f, y2 = 0.f;
    if (sc > SCORE_T) {
      int n = (int)(0xFFFFFFFFu - (uint32_t)key);
      const float* rp; int local, Nl, logW; float st;
      if (n < 65536)      { rp = r0p + (size_t)b * 4 * 65536; local = n;          Nl = 65536; logW = 8; st = 8.f;  }
      else if (n < 81920) { rp = r1p + (size_t)b * 4 * 16384; local = n - 65536;  Nl = 16384; logW = 7; st = 16.f; }
      else if (n < 86016) { rp = r2p + (size_t)b * 4 * 4096;  local = n - 81920;  Nl = 4096;  logW = 6; st = 32.f; }
      else                { rp = r3p + (size_t)b * 4 * 1024;  local = n - 86016;  Nl = 1024;  logW = 5; st = 64.f; }
      int y = local >> logW, x = local & ((1 << logW) - 1);
      float cx = ((float)x + 0.5f) * st;
      float cy = ((float)y + 0.5f) * st;
      float rv0 = rp[local];
      float rv1 = rp[Nl + local];
      float rv2 = rp[2 * Nl + local];
      float rv3 = rp[3 * Nl + local];
      float cxd = cx + rv0 * st;
      float cyd = cy + rv1 * st;
      float w = expf(rv2) * st;
      float h = expf(rv3) * st;
      x1 = cxd - w * 0.5f; y1 = cyd - h * 0.5f;
      x2 = cxd + w * 0.5f; y2 = cyd + h * 0.5f;
    }
    skeys[(size_t)b * KSEL + t] = key;
    float* base = bxs + (size_t)b * 5 * KSEL;
    base[t]            = x1;
    base[KSEL + t]     = y1;
    base[2 * KSEL + t] = x2;
    base[3 * KSEL + t] = y2;
    base[4 * KSEL + t] = (x2 - x1) * (y2 - y1);
  }
}

// ---------------- pass 5: suppression matrix (parallel across 128 blocks) ----------------
__global__ __launch_bounds__(512)
void k_sup(const float* __restrict__ bxs, uint64_t* __restrict__ sup) {
  const int b = blockIdx.x >> 3, chunk = blockIdx.x & 7;  // 64 rows per block
  const int tid = threadIdx.x, wave = tid >> 6, lane = tid & 63;

  __shared__ float sx1[KSEL], sy1[KSEL], sx2[KSEL], sy2[KSEL], sar[KSEL];
  const float* base = bxs + (size_t)b * 5 * KSEL;
  // 512 threads: each loads exactly its own element (was the round-3 OOB bug)
  sx1[tid] = base[tid];
  sy1[tid] = base[KSEL + tid];
  sx2[tid] = base[2 * KSEL + tid];
  sy2[tid] = base[3 * KSEL + tid];
  sar[tid] = base[4 * KSEL + tid];
  __syncthreads();

  for (int task = wave; task < 512; task += 8) {
    int i = (chunk << 6) + (task >> 3);
    int w = task & 7;
    int jj = (w << 6) | lane;
    float xx1 = fmaxf(sx1[i], sx1[jj]);
    float yy1 = fmaxf(sy1[i], sy1[jj]);
    float xx2 = fminf(sx2[i], sx2[jj]);
    float yy2 = fminf(sy2[i], sy2[jj]);
    float inter = fmaxf(xx2 - xx1, 0.f) * fmaxf(yy2 - yy1, 0.f);
    float uni = sar[i] + sar[jj] - inter;
    float iou = inter / fmaxf(uni, 1e-9f);
    bool pred = (jj > i) && (iou > NMS_T);
    unsigned long long word = __ballot(pred);
    if (lane == 0) sup[((size_t)b * KSEL + i) * 8 + w] = word;
  }
}

// ---------------- pass 6: serial sweep (early-exit) + output ----------------
__global__ __launch_bounds__(1024)
void k_sweep(const uint64_t* __restrict__ skeys, const float* __restrict__ bxs,
             const uint64_t* __restrict__ sup,
             const float* __restrict__ p0, const float* __restrict__ p1,
             const float* __restrict__ p2, const float* __restrict__ p3,
             float* __restrict__ out) {
  const int b = blockIdx.x;
  const int tid = threadIdx.x;

  __shared__ uint64_t ssup[KSEL][8];     // 32 KB
  __shared__ uint64_t skey[KSEL];        // 4 KB
  __shared__ uint64_t keepW[8];
  __shared__ int      s_nkept;

  uint64_t* sf = &ssup[0][0];
  for (int i = tid; i < KSEL * 8; i += 1024) sf[i] = sup[(size_t)b * KSEL * 8 + i];
  if (tid < KSEL) skey[tid] = skeys[(size_t)b * KSEL + tid];
  __syncthreads();

  {
    int wave = tid >> 6, lane = tid & 63;
    if (wave < 8) {
      float sc = __uint_as_float((uint32_t)(skey[tid] >> 32));
      unsigned long long v = __ballot(sc > SCORE_T);
      if (lane == 0) keepW[wave] = v;
    }
  }
  __syncthreads();

  if (tid == 0) {
    uint64_t kw[8];
#pragma unroll
    for (int w = 0; w < 8; ++w) kw[w] = keepW[w];
    int nk = 0;
    bool done = false;
#pragma unroll
    for (int w = 0; w < 8; ++w) {
      if (!done) {
        uint64_t rem = kw[w];
        while (rem) {
          int bit = __ffsll((unsigned long long)rem) - 1;
          rem &= rem - 1;
          if (!((kw[w] >> bit) & 1ull)) continue;  // suppressed meanwhile
          int i = (w << 6) | bit;
#pragma unroll
          for (int u = 0; u < 8; ++u) kw[u] &= ~ssup[i][u];
          ++nk;
          if (nk >= MAXDET) { done = true; break; }
        }
      }
    }
#pragma unroll
    for (int w = 0; w < 8; ++w) keepW[w] = kw[w];
    s_nkept = nk;
  }
  __syncthreads();

  int nwrite = s_nkept; if (nwrite > MAXDET) nwrite = MAXDET;

  // write kept rows
  if (tid < KSEL) {
    int w = tid >> 6, bit = tid & 63;
    bool kept = (keepW[w] >> bit) & 1ull;
    if (kept) {
      int r = 0;
#pragma unroll
      for (int u = 0; u < 8; ++u) {
        uint64_t m = keepW[u];
        if (u < w) r += __popcll(m);
        else if (u == w) r += __popcll(m & ((bit == 0) ? 0ull : ((1ull << bit) - 1ull)));
      }
      if (r < MAXDET) {
        uint64_t key = skey[tid];
        float sc = __uint_as_float((uint32_t)(key >> 32));
        int n = (int)(0xFFFFFFFFu - (uint32_t)key);
        const float* kp; int local, Nl, logW; float st;
        if (n < 65536)      { kp = p0 + (size_t)b * 10 * 65536; local = n;          Nl = 65536; logW = 8; st = 8.f;  }
        else if (n < 81920) { kp = p1 + (size_t)b * 10 * 16384; local = n - 65536;  Nl = 16384; logW = 7; st = 16.f; }
        else if (n < 86016) { kp = p2 + (size_t)b * 10 * 4096;  local = n - 81920;  Nl = 4096;  logW = 6; st = 32.f; }
        else                { kp = p3 + (size_t)b * 10 * 1024;  local = n - 86016;  Nl = 1024;  logW = 5; st = 64.f; }
        int y = local >> logW, x = local & ((1 << logW) - 1);
        float cx = ((float)x + 0.5f) * st;
        float cy = ((float)y + 0.5f) * st;
        const float* bb = bxs + (size_t)b * 5 * KSEL;
        float* o = out + ((size_t)b * MAXDET + r) * 15;
        o[0] = bb[tid];
        o[1] = bb[KSEL + tid];
        o[2] = bb[2 * KSEL + tid];
        o[3] = bb[3 * KSEL + tid];
        o[4] = sc;
#pragma unroll
        for (int q = 0; q < 5; ++q) {
          float kx = cx + kp[(2 * q) * Nl + local] * st;
          float ky = cy + kp[(2 * q + 1) * Nl + local] * st;
          o[5 + 2 * q] = kx;
          o[6 + 2 * q] = ky;
        }
      }
    }
  }

  // zero-fill remaining rows
  if (tid < MAXDET && tid >= nwrite) {
    float* o = out + ((size_t)b * MAXDET + tid) * 15;
#pragma unroll
    for (int e = 0; e < 15; ++e) o[e] = 0.f;
  }
}

extern "C" void kernel_launch(void* const* d_in, const int* in_sizes, int n_in,
                              void* d_out, int out_size, void* d_ws, size_t ws_size,
                              hipStream_t stream) {
  const float* cls0 = (const float*)d_in[0];
  const float* reg0 = (const float*)d_in[1];
  const float* kpt0 = (const float*)d_in[2];
  const float* cls1 = (const float*)d_in[3];
  const float* reg1 = (const float*)d_in[4];
  const float* kpt1 = (const float*)d_in[5];
  const float* cls2 = (const float*)d_in[6];
  const float* reg2 = (const float*)d_in[7];
  const float* kpt2 = (const float*)d_in[8];
  const float* cls3 = (const float*)d_in[9];
  const float* reg3 = (const float*)d_in[10];
  const float* kpt3 = (const float*)d_in[11];
  float* out = (float*)d_out;

  uint8_t* ws = (uint8_t*)d_ws;
  // layout (sup aliases keys — keys are dead after k_sort):
  //   hist @ 0 (4608) | cnt @ 4608 (64) | thr @ 4672 (64)
  //   skeys @ 8192 (64K) | bxs @ 73728 (160K) | keys/sup @ 237568 (512K)
  uint32_t* hist  = (uint32_t*)ws;
  uint32_t* cnt   = (uint32_t*)(ws + 4608);
  uint32_t* thr   = (uint32_t*)(ws + 4672);
  uint64_t* skeys = (uint64_t*)(ws + 8192);
  float*    bxs   = (float*)   (ws + 73728);
  uint64_t* keys  = (uint64_t*)(ws + 237568);
  uint64_t* sup   = (uint64_t*)(ws + 237568);

  hipMemsetAsync(ws, 0, 8192, stream);

  k_scan<<<NIMG * SLICES, 1024, 0, stream>>>(cls0, cls1, cls2, cls3, hist);
  k_thresh<<<NIMG, 64, 0, stream>>>(hist, thr);
  k_compact<<<NIMG * SLICES, 1024, 0, stream>>>(cls0, cls1, cls2, cls3, thr, cnt, keys);
  k_sort<<<NIMG, 1024, 0, stream>>>(keys, cnt, reg0, reg1, reg2, reg3, skeys, bxs);
  k_sup<<<NIMG * 8, 512, 0, stream>>>(bxs, sup);
  k_sweep<<<NIMG, 1024, 0, stream>>>(skeys, bxs, sup,
                                     kpt0, kpt1, kpt2, kpt3, out);
}

// Round 5
// 102.314 us; speedup vs baseline: 5.6304x; 1.0902x over previous
//
#include <hip/hip_runtime.h>
#include <stdint.h>

#define CAP_   2048
#define KSEL   512
#define MAXDET 300
#define NIMG   16
#define SCORE_T 0.25f
#define NMS_T   0.45f
#define HBINS  72          // 65 used (buckets 4000..4064 of bits>>18)
#define SLICES 8
#define PERSLICE 2720      // (87040/4) / 8

// anchor-level boundaries: 65536, 81920, 86016, 87040 ; strides 8,16,32,64
// float4-group boundaries: 16384, 20480, 21504, 21760

__device__ __forceinline__ float sigmoidf_(float x) {
  return 1.0f / (1.0f + expf(-x));
}

__device__ __forceinline__ float4 load_cls4_(const float* c0, const float* c1,
                                             const float* c2, const float* c3,
                                             int b, int g) {
  if (g < 16384) return ((const float4*)(c0 + (size_t)b * 65536))[g];
  if (g < 20480) return ((const float4*)(c1 + (size_t)b * 16384))[g - 16384];
  if (g < 21504) return ((const float4*)(c2 + (size_t)b * 4096))[g - 20480];
  return ((const float4*)(c3 + (size_t)b * 1024))[g - 21504];
}

// ---------------- pass 1: 65-bin score histogram, LDS-privatized ----------------
__global__ __launch_bounds__(1024)
void k_scan(const float* __restrict__ c0, const float* __restrict__ c1,
            const float* __restrict__ c2, const float* __restrict__ c3,
            uint32_t* __restrict__ hist) {
  const int b = blockIdx.x >> 3;
  const int slice = blockIdx.x & 7;
  const int tid = threadIdx.x;
  const int wave = tid >> 6;

  __shared__ uint32_t lh[16][HBINS];
  for (int i = tid; i < 16 * HBINS; i += 1024) ((uint32_t*)lh)[i] = 0;
  __syncthreads();

  for (int it = 0; it < 3; ++it) {
    int lg = it * 1024 + tid;
    if (lg < PERSLICE) {
      int g = slice * PERSLICE + lg;
      float4 v = load_cls4_(c0, c1, c2, c3, b, g);
      float sv[4] = {v.x, v.y, v.z, v.w};
#pragma unroll
      for (int e = 0; e < 4; ++e) {
        float s = sigmoidf_(sv[e]);
        if (s > SCORE_T) {
          uint32_t bin = (__float_as_uint(s) >> 18) - 4000u;
          if (bin > 64u) bin = 64u;
          atomicAdd(&lh[wave][bin], 1u);
        }
      }
    }
  }
  __syncthreads();

  if (tid < HBINS) {
    uint32_t s = 0;
#pragma unroll
    for (int w = 0; w < 16; ++w) s += lh[w][tid];
    if (s) atomicAdd(&hist[b * HBINS + tid], s);
  }
}

// ---------------- pass 2: per-image bit threshold (1 wave per image) ----------------
__global__ void k_thresh(const uint32_t* __restrict__ hist, uint32_t* __restrict__ thr) {
  const int b = blockIdx.x;
  const int lane = threadIdx.x;           // 64 threads
  uint32_t x = hist[b * HBINS + lane];
  if (lane == 63) x += hist[b * HBINS + 64];

  for (int off = 1; off < 64; off <<= 1) {
    uint32_t v = __shfl_down(x, off);
    if (lane + off < 64) x += v;
  }
  uint32_t nxt = __shfl_down(x, 1);
  if (lane == 63) nxt = 0;
  bool cross = (x >= KSEL) && (nxt < KSEL);
  unsigned long long m = __ballot(cross);
  if (lane == 0) {
    int bucket = m ? (__ffsll(m) - 1) : 0;
    thr[b] = ((uint32_t)(4000 + bucket)) << 18;
  }
}

// ---------------- pass 3: compact candidates via LDS list ----------------
__global__ __launch_bounds__(1024)
void k_compact(const float* __restrict__ c0, const float* __restrict__ c1,
               const float* __restrict__ c2, const float* __restrict__ c3,
               const uint32_t* __restrict__ thr,
               uint32_t* __restrict__ cnt, uint64_t* __restrict__ keys) {
  const int b = blockIdx.x >> 3;
  const int slice = blockIdx.x & 7;
  const int tid = threadIdx.x;

  __shared__ uint64_t lk[CAP_];
  __shared__ uint32_t lcnt;
  __shared__ uint32_t gbase;
  if (tid == 0) lcnt = 0;
  __syncthreads();

  const uint32_t tb = thr[b];

  for (int it = 0; it < 3; ++it) {
    int lg = it * 1024 + tid;
    if (lg < PERSLICE) {
      int g = slice * PERSLICE + lg;
      float4 v = load_cls4_(c0, c1, c2, c3, b, g);
      float sv[4] = {v.x, v.y, v.z, v.w};
#pragma unroll
      for (int e = 0; e < 4; ++e) {
        float s = sigmoidf_(sv[e]);
        if (s > SCORE_T) {
          uint32_t bits = __float_as_uint(s);
          if (bits >= tb) {
            uint32_t n = (uint32_t)(4 * g + e);
            uint32_t p = atomicAdd(&lcnt, 1u);
            if (p < CAP_)
              lk[p] = ((uint64_t)bits << 32) | (0xFFFFFFFFu - n);
          }
        }
      }
    }
  }
  __syncthreads();

  if (tid == 0) {
    uint32_t c = lcnt > CAP_ ? CAP_ : lcnt;
    gbase = atomicAdd(&cnt[b], c);
  }
  __syncthreads();

  uint32_t c = lcnt > CAP_ ? CAP_ : lcnt;
  for (uint32_t i = tid; i < c; i += 1024) {
    uint32_t pos = gbase + i;
    if (pos < CAP_) keys[(size_t)b * CAP_ + pos] = lk[i];
  }
}

// ---------------- pass 4: hybrid register/LDS bitonic sort + decode ----------------
__device__ __forceinline__ uint64_t cmpex_(uint64_t a, uint64_t b, bool takemax) {
  bool agtb = a > b;
  return (takemax == agtb) ? a : b;
}

__global__ __launch_bounds__(1024)
void k_sort(const uint64_t* __restrict__ keys, const uint32_t* __restrict__ cnt,
            const float* __restrict__ r0p, const float* __restrict__ r1p,
            const float* __restrict__ r2p, const float* __restrict__ r3p,
            uint64_t* __restrict__ skeys, float* __restrict__ bxs) {
  const int b = blockIdx.x;
  const int t = threadIdx.x;

  __shared__ uint64_t sk[CAP_];          // 16 KB

  int c = (int)cnt[b];
  if (c > CAP_) c = CAP_;
  uint64_t r0 = (t < c)        ? keys[(size_t)b * CAP_ + t]        : 0ull;
  uint64_t r1 = (t + 1024 < c) ? keys[(size_t)b * CAP_ + t + 1024] : 0ull;

  // element i0 = t held in r0, element i1 = t+1024 held in r1; descending sort
  for (int k = 2; k <= CAP_; k <<= 1) {
    bool asc0 = (t & k) != 0;
    bool asc1 = ((t + 1024) & k) != 0;
    int j = k >> 1;
    if (j == 1024) {            // k==2048: partner is own other register; both desc
      if (r0 < r1) { uint64_t tmp = r0; r0 = r1; r1 = tmp; }
      j = 512;
    }
    for (; j >= 64; j >>= 1) {  // cross-wave rounds via LDS
      sk[t] = r0; sk[t + 1024] = r1;
      __syncthreads();
      uint64_t u0 = sk[t ^ j];
      uint64_t u1 = sk[(t ^ j) + 1024];
      __syncthreads();
      bool lo = (t & j) == 0;
      r0 = cmpex_(r0, u0, asc0 ? !lo : lo);
      r1 = cmpex_(r1, u1, asc1 ? !lo : lo);
    }
    for (; j >= 1; j >>= 1) {   // intra-wave rounds via shuffle
      uint64_t u0 = __shfl_xor((unsigned long long)r0, j);
      uint64_t u1 = __shfl_xor((unsigned long long)r1, j);
      bool lo = (t & j) == 0;
      r0 = cmpex_(r0, u0, asc0 ? !lo : lo);
      r1 = cmpex_(r1, u1, asc1 ? !lo : lo);
    }
  }
  sk[t] = r0; sk[t + 1024] = r1;
  __syncthreads();

  // decode top-512 boxes, store keys + SoA boxes/areas to workspace
  if (t < KSEL) {
    uint64_t key = sk[t];
    float sc = __uint_as_float((uint32_t)(key >> 32));
    float x1 = 0.f, y1 = 0.f, x2 = 0.f, y2 = 0.f;
    if (sc > SCORE_T) {
      int n = (int)(0xFFFFFFFFu - (uint32_t)key);
      const float* rp; int local, Nl, logW; float st;
      if (n < 65536)      { rp = r0p + (size_t)b * 4 * 65536; local = n;          Nl = 65536; logW = 8; st = 8.f;  }
      else if (n < 81920) { rp = r1p + (size_t)b * 4 * 16384; local = n - 65536;  Nl = 16384; logW = 7; st = 16.f; }
      else if (n < 86016) { rp = r2p + (size_t)b * 4 * 4096;  local = n - 81920;  Nl = 4096;  logW = 6; st = 32.f; }
      else                { rp = r3p + (size_t)b * 4 * 1024;  local = n - 86016;  Nl = 1024;  logW = 5; st = 64.f; }
      int y = local >> logW, x = local & ((1 << logW) - 1);
      float cx = ((float)x + 0.5f) * st;
      float cy = ((float)y + 0.5f) * st;
      float rv0 = rp[local];
      float rv1 = rp[Nl + local];
      float rv2 = rp[2 * Nl + local];
      float rv3 = rp[3 * Nl + local];
      float cxd = cx + rv0 * st;
      float cyd = cy + rv1 * st;
      float w = expf(rv2) * st;
      float h = expf(rv3) * st;
      x1 = cxd - w * 0.5f; y1 = cyd - h * 0.5f;
      x2 = cxd + w * 0.5f; y2 = cyd + h * 0.5f;
    }
    skeys[(size_t)b * KSEL + t] = key;
    float* base = bxs + (size_t)b * 5 * KSEL;
    base[t]            = x1;
    base[KSEL + t]     = y1;
    base[2 * KSEL + t] = x2;
    base[3 * KSEL + t] = y2;
    base[4 * KSEL + t] = (x2 - x1) * (y2 - y1);
  }
}

// ---------------- pass 5: suppression matrix (parallel across 128 blocks) ----------------
__global__ __launch_bounds__(512)
void k_sup(const float* __restrict__ bxs, uint64_t* __restrict__ sup) {
  const int b = blockIdx.x >> 3, chunk = blockIdx.x & 7;  // 64 rows per block
  const int tid = threadIdx.x, wave = tid >> 6, lane = tid & 63;

  __shared__ float sx1[KSEL], sy1[KSEL], sx2[KSEL], sy2[KSEL], sar[KSEL];
  const float* base = bxs + (size_t)b * 5 * KSEL;
  sx1[tid] = base[tid];
  sy1[tid] = base[KSEL + tid];
  sx2[tid] = base[2 * KSEL + tid];
  sy2[tid] = base[3 * KSEL + tid];
  sar[tid] = base[4 * KSEL + tid];
  __syncthreads();

  for (int task = wave; task < 512; task += 8) {
    int i = (chunk << 6) + (task >> 3);
    int w = task & 7;
    int jj = (w << 6) | lane;
    float xx1 = fmaxf(sx1[i], sx1[jj]);
    float yy1 = fmaxf(sy1[i], sy1[jj]);
    float xx2 = fminf(sx2[i], sx2[jj]);
    float yy2 = fminf(sy2[i], sy2[jj]);
    float inter = fmaxf(xx2 - xx1, 0.f) * fmaxf(yy2 - yy1, 0.f);
    float uni = sar[i] + sar[jj] - inter;
    float iou = inter / fmaxf(uni, 1e-9f);
    bool pred = (jj > i) && (iou > NMS_T);
    unsigned long long word = __ballot(pred);
    if (lane == 0) sup[((size_t)b * KSEL + i) * 8 + w] = word;
  }
}

// ---------------- pass 6: chunked register-resident sweep + output ----------------
__global__ __launch_bounds__(1024)
void k_sweep(const uint64_t* __restrict__ skeys, const float* __restrict__ bxs,
             const uint64_t* __restrict__ sup,
             const float* __restrict__ p0, const float* __restrict__ p1,
             const float* __restrict__ p2, const float* __restrict__ p3,
             float* __restrict__ out) {
  const int b = blockIdx.x;
  const int tid = threadIdx.x;
  const int wave = tid >> 6, lane = tid & 63;

  __shared__ uint64_t ssup[KSEL][8];     // 32 KB
  __shared__ uint64_t skey[KSEL];        // 4 KB
  __shared__ uint64_t keepW[8];
  __shared__ int      s_nkept;

  uint64_t* sf = &ssup[0][0];
  for (int i = tid; i < KSEL * 8; i += 1024) sf[i] = sup[(size_t)b * KSEL * 8 + i];
  if (tid < KSEL) skey[tid] = skeys[(size_t)b * KSEL + tid];
  __syncthreads();

  if (wave < 8) {
    float sc = __uint_as_float((uint32_t)(skey[tid] >> 32));
    unsigned long long v = __ballot(sc > SCORE_T);
    if (lane == 0) keepW[wave] = v;
  }
  __syncthreads();

  // Chunked greedy sweep, entirely in wave 0 registers (no LDS in the chain).
  if (wave == 0) {
    uint64_t kw0 = keepW[0], kw1 = keepW[1], kw2 = keepW[2], kw3 = keepW[3];
    uint64_t kw4 = keepW[4], kw5 = keepW[5], kw6 = keepW[6], kw7 = keepW[7];

#define SWEEP_CHUNK(CCH, KWC)                                                  \
    {                                                                          \
      int i = (CCH << 6) | lane;                                               \
      uint64_t row0 = ssup[i][0], row1 = ssup[i][1], row2 = ssup[i][2],        \
               row3 = ssup[i][3], row4 = ssup[i][4], row5 = ssup[i][5],        \
               row6 = ssup[i][6], row7 = ssup[i][7];                           \
      uint64_t intra = __shfl((unsigned long long)row0, 0); /* placeholder */  \
      (void)intra;                                                             \
      uint64_t myintra;                                                        \
      switch (CCH) {                                                           \
        case 0: myintra = row0; break; case 1: myintra = row1; break;          \
        case 2: myintra = row2; break; case 3: myintra = row3; break;          \
        case 4: myintra = row4; break; case 5: myintra = row5; break;          \
        case 6: myintra = row6; break; default: myintra = row7; break;         \
      }                                                                        \
      uint64_t alive = KWC;                                                    \
      uint64_t rem = alive;                                                    \
      while (rem) {                                                            \
        int bq = __ffsll((unsigned long long)rem) - 1;                         \
        rem &= rem - 1;                                                        \
        uint64_t rowb = __shfl((unsigned long long)myintra, bq);               \
        alive &= ~rowb;                                                        \
        rem &= ~rowb;                                                          \
      }                                                                        \
      KWC = alive;                                                             \
      uint64_t take = ((alive >> lane) & 1ull) ? ~0ull : 0ull;                 \
      uint64_t v0 = row0 & take, v1 = row1 & take, v2 = row2 & take,           \
               v3 = row3 & take, v4 = row4 & take, v5 = row5 & take,           \
               v6 = row6 & take, v7 = row7 & take;                             \
      _Pragma("unroll")                                                        \
      for (int s = 1; s < 64; s <<= 1) {                                       \
        v0 |= __shfl_xor((unsigned long long)v0, s);                           \
        v1 |= __shfl_xor((unsigned long long)v1, s);                           \
        v2 |= __shfl_xor((unsigned long long)v2, s);                           \
        v3 |= __shfl_xor((unsigned long long)v3, s);                           \
        v4 |= __shfl_xor((unsigned long long)v4, s);                           \
        v5 |= __shfl_xor((unsigned long long)v5, s);                           \
        v6 |= __shfl_xor((unsigned long long)v6, s);                           \
        v7 |= __shfl_xor((unsigned long long)v7, s);                           \
      }                                                                        \
      if (CCH < 1) kw1 &= ~v1; if (CCH < 2) kw2 &= ~v2;                        \
      if (CCH < 3) kw3 &= ~v3; if (CCH < 4) kw4 &= ~v4;                        \
      if (CCH < 5) kw5 &= ~v5; if (CCH < 6) kw6 &= ~v6;                        \
      if (CCH < 7) kw7 &= ~v7;                                                 \
      (void)v0;                                                                \
    }

    SWEEP_CHUNK(0, kw0)
    SWEEP_CHUNK(1, kw1)
    SWEEP_CHUNK(2, kw2)
    SWEEP_CHUNK(3, kw3)
    SWEEP_CHUNK(4, kw4)
    SWEEP_CHUNK(5, kw5)
    SWEEP_CHUNK(6, kw6)
    SWEEP_CHUNK(7, kw7)
#undef SWEEP_CHUNK

    if (lane == 0) {
      keepW[0] = kw0; keepW[1] = kw1; keepW[2] = kw2; keepW[3] = kw3;
      keepW[4] = kw4; keepW[5] = kw5; keepW[6] = kw6; keepW[7] = kw7;
      s_nkept = __popcll(kw0) + __popcll(kw1) + __popcll(kw2) + __popcll(kw3) +
                __popcll(kw4) + __popcll(kw5) + __popcll(kw6) + __popcll(kw7);
    }
  }
  __syncthreads();

  int nwrite = s_nkept; if (nwrite > MAXDET) nwrite = MAXDET;

  // write kept rows
  if (tid < KSEL) {
    int w = tid >> 6, bit = tid & 63;
    bool kept = (keepW[w] >> bit) & 1ull;
    if (kept) {
      int r = 0;
#pragma unroll
      for (int u = 0; u < 8; ++u) {
        uint64_t m = keepW[u];
        if (u < w) r += __popcll(m);
        else if (u == w) r += __popcll(m & ((bit == 0) ? 0ull : ((1ull << bit) - 1ull)));
      }
      if (r < MAXDET) {
        uint64_t key = skey[tid];
        float sc = __uint_as_float((uint32_t)(key >> 32));
        int n = (int)(0xFFFFFFFFu - (uint32_t)key);
        const float* kp; int local, Nl, logW; float st;
        if (n < 65536)      { kp = p0 + (size_t)b * 10 * 65536; local = n;          Nl = 65536; logW = 8; st = 8.f;  }
        else if (n < 81920) { kp = p1 + (size_t)b * 10 * 16384; local = n - 65536;  Nl = 16384; logW = 7; st = 16.f; }
        else if (n < 86016) { kp = p2 + (size_t)b * 10 * 4096;  local = n - 81920;  Nl = 4096;  logW = 6; st = 32.f; }
        else                { kp = p3 + (size_t)b * 10 * 1024;  local = n - 86016;  Nl = 1024;  logW = 5; st = 64.f; }
        int y = local >> logW, x = local & ((1 << logW) - 1);
        float cx = ((float)x + 0.5f) * st;
        float cy = ((float)y + 0.5f) * st;
        const float* bb = bxs + (size_t)b * 5 * KSEL;
        float* o = out + ((size_t)b * MAXDET + r) * 15;
        o[0] = bb[tid];
        o[1] = bb[KSEL + tid];
        o[2] = bb[2 * KSEL + tid];
        o[3] = bb[3 * KSEL + tid];
        o[4] = sc;
#pragma unroll
        for (int q = 0; q < 5; ++q) {
          float kx = cx + kp[(2 * q) * Nl + local] * st;
          float ky = cy + kp[(2 * q + 1) * Nl + local] * st;
          o[5 + 2 * q] = kx;
          o[6 + 2 * q] = ky;
        }
      }
    }
  }

  // zero-fill remaining rows
  if (tid < MAXDET && tid >= nwrite) {
    float* o = out + ((size_t)b * MAXDET + tid) * 15;
#pragma unroll
    for (int e = 0; e < 15; ++e) o[e] = 0.f;
  }
}

extern "C" void kernel_launch(void* const* d_in, const int* in_sizes, int n_in,
                              void* d_out, int out_size, void* d_ws, size_t ws_size,
                              hipStream_t stream) {
  const float* cls0 = (const float*)d_in[0];
  const float* reg0 = (const float*)d_in[1];
  const float* kpt0 = (const float*)d_in[2];
  const float* cls1 = (const float*)d_in[3];
  const float* reg1 = (const float*)d_in[4];
  const float* kpt1 = (const float*)d_in[5];
  const float* cls2 = (const float*)d_in[6];
  const float* reg2 = (const float*)d_in[7];
  const float* kpt2 = (const float*)d_in[8];
  const float* cls3 = (const float*)d_in[9];
  const float* reg3 = (const float*)d_in[10];
  const float* kpt3 = (const float*)d_in[11];
  float* out = (float*)d_out;

  uint8_t* ws = (uint8_t*)d_ws;
  // layout (sup aliases keys — keys are dead after k_sort):
  //   hist @ 0 (4608) | cnt @ 4608 (64) | thr @ 4672 (64)
  //   skeys @ 8192 (64K) | bxs @ 73728 (160K) | keys/sup @ 237568 (512K)
  uint32_t* hist  = (uint32_t*)ws;
  uint32_t* cnt   = (uint32_t*)(ws + 4608);
  uint32_t* thr   = (uint32_t*)(ws + 4672);
  uint64_t* skeys = (uint64_t*)(ws + 8192);
  float*    bxs   = (float*)   (ws + 73728);
  uint64_t* keys  = (uint64_t*)(ws + 237568);
  uint64_t* sup   = (uint64_t*)(ws + 237568);

  hipMemsetAsync(ws, 0, 8192, stream);

  k_scan<<<NIMG * SLICES, 1024, 0, stream>>>(cls0, cls1, cls2, cls3, hist);
  k_thresh<<<NIMG, 64, 0, stream>>>(hist, thr);
  k_compact<<<NIMG * SLICES, 1024, 0, stream>>>(cls0, cls1, cls2, cls3, thr, cnt, keys);
  k_sort<<<NIMG, 1024, 0, stream>>>(keys, cnt, reg0, reg1, reg2, reg3, skeys, bxs);
  k_sup<<<NIMG * 8, 512, 0, stream>>>(bxs, sup);
  k_sweep<<<NIMG, 1024, 0, stream>>>(skeys, bxs, sup,
                                     kpt0, kpt1, kpt2, kpt3, out);
}